// Round 11
// baseline (504.698 us; speedup 1.0000x reference)
//
#include <hip/hip_runtime.h>
#include <hip/hip_bf16.h>
#include <stdint.h>
#include <stddef.h>

// Problem dims (fixed): B=64, C=128, H=W=56, 3x3 conv pad=1 stride=1.
#define CH 128
#define HH 56
#define WW 56
#define HWPIX (HH*WW)        // 3136
#define NB 64
#define NPIXF 200704.0f      // B*H*W
#define NCONVBLK 1568        // 32 sample-pairs x 49 tiles (8x8 px, 2 samples/blk)

typedef __attribute__((ext_vector_type(8))) short short8v;    // 8 bf16 -> MFMA A/B frag
typedef __attribute__((ext_vector_type(8))) unsigned short bfv8;
typedef __attribute__((ext_vector_type(4))) unsigned short bfv4;
typedef __attribute__((ext_vector_type(4))) float f32x4;

__device__ __forceinline__ unsigned short f2bf(float f) {
  unsigned int u = __float_as_uint(f);
  u += 0x7fffu + ((u >> 16) & 1u);            // RNE
  return (unsigned short)(u >> 16);
}
__device__ __forceinline__ float bf2f(unsigned short s) {
  return __uint_as_float(((unsigned int)s) << 16);
}

// ---------------------------------------------------------------------------
// K1: x NCHW fp32 -> NHWC bf16 (LDS transpose, coalesced 16B/lane writes).
__global__ __launch_bounds__(256)
void prep_x(const float* __restrict__ x, unsigned short* __restrict__ xT) {
  __shared__ unsigned short tile[4 * 56 * 128];
  const int bid = blockIdx.x;
  const int b = bid / 14, hq = bid % 14;
  const int hl = threadIdx.x >> 6;
  const int h = hq * 4 + hl;
  const int w = threadIdx.x & 63;
  if (w < WW) {
    const float* src = x + (size_t)b * CH * HWPIX + h * WW + w;
    const int pos = hl * WW + w;
    #pragma unroll 4
    for (int c0 = 0; c0 < CH; c0 += 8) {
      bfv8 v;
      #pragma unroll
      for (int k = 0; k < 8; ++k) v[k] = f2bf(src[(size_t)(c0 + k) * HWPIX]);
      const int idx = (pos * CH + c0) ^ ((pos & 7) << 3);
      *(bfv8*)(tile + idx) = v;
    }
  }
  __syncthreads();
  unsigned short* out = xT + (size_t)(b * HH + hq * 4) * WW * CH;
  #pragma unroll
  for (int j = 0; j < 14; ++j) {
    const int u = j * 256 + threadIdx.x;
    const int idx = (u * 8) ^ (((u >> 4) & 7) << 3);
    *(bfv8*)(out + u * 8) = *(const bfv8*)(tile + idx);
  }
}

// ---------------------------------------------------------------------------
// K2: weights [B,O,I,3,3] fp32 -> [B,tap,O,I] bf16 (dense reads, 16B writes).
__global__ __launch_bounds__(256)
void prep_w(const float* __restrict__ w1, const float* __restrict__ w2,
            unsigned short* __restrict__ o1, unsigned short* __restrict__ o2) {
  __shared__ unsigned short lw[18432];
  const int id = blockIdx.x;
  const int which = id >> 9;
  const int b = (id >> 3) & 63, ck = id & 7;
  const float* src = (which ? w2 : w1) + ((size_t)b * 16384 + ck * 2048) * 9;
  unsigned short* dst = (which ? o2 : o1);
  const int t = threadIdx.x;
  #pragma unroll
  for (int j = 0; j < 72; ++j)
    lw[j * 256 + t] = f2bf(src[j * 256 + t]);
  __syncthreads();
  const int ol = t >> 4, oct = t & 15;
  #pragma unroll
  for (int tap = 0; tap < 9; ++tap) {
    bfv8 v;
    #pragma unroll
    for (int k = 0; k < 8; ++k) v[k] = lw[(ol * 128 + oct * 8 + k) * 9 + tap];
    *(bfv8*)(dst + ((size_t)(b * 9 + tap) * CH + ck * 16 + ol) * CH + oct * 8) = v;
  }
}

// ---------------------------------------------------------------------------
// K3/K5: per-sample conv, implicit GEMM.
// R19: R18's 64O x 64px-per-wave structure with the BUG FIXED. R18's absmax
// 10.4 was patch row stride 120 < 128 (row data is 128 shorts): every row's
// channels 120-127 were clobbered by the next row's 0-7 during staging.
// Stride restored to 136 (16B-aligned, known-good bank class from R8-R17).
// LDS: patch 2x100x136 (54,400B) + wbuf 32,768 + sacc 1,024 = 88,192 ->
// 1 block/CU (8 waves = 2/SIMD, exactly R8's proven-sufficient residency;
// occupancy was proven not the lever in R13/R16). DS-volume intent intact:
// 8 b128 reads per 16 MFMA (0.5/MFMA vs R16's 0.75; per-sample-tile DS reads
// 864 -> 576, -33%). Pipeline discipline identical to proven-correct R16/17.
// Predict: absmax pass; conv 153->110-135 (MfmaUtil 20-26) if DS-volume
// model right; VGPR 80-100, FETCH ~34MB (inflation = spill = abort).
// Pre-committed null: conv >=145 clean -> conv locally converged, pivot to
// aux kernels (prep_x/final ~55us above HBM floors).
template<bool FUSE>
__global__ __launch_bounds__(256, 2)
void conv_kernel(const unsigned short* __restrict__ in,
                 const unsigned short* __restrict__ wt,
                 unsigned short* __restrict__ outp,
                 float* __restrict__ partials,
                 const float* __restrict__ tab) {   // [256]: scale | shift (FUSE)
  __shared__ __align__(16) unsigned short patch[27200];  // 2 x 100 rows x 136
  __shared__ __align__(16) unsigned short wbuf[16384];   // 4 wv x 2 buf x 2048
  __shared__ float sacc[256];                            // sum[128] | sumsq[128]
  const int xcd = blockIdx.x & 7;
  const int q = blockIdx.x >> 3;                    // 0..195
  const int pr = q / 49;
  const int tile = q - pr * 49;                     // 0..48
  const int pair = pr * 8 + xcd;                    // 0..31
  const int ty = tile / 7, tx = tile % 7;
  const int h0 = ty * 8, w0 = tx * 8;
  const int t = threadIdx.x;

  const int lane = t & 63, wv = t >> 6;
  const int lrow = lane & 15, lgrp = lane >> 4;
  const int px = lrow & 7, pyl = lrow >> 3;

  const int sv = wv >> 1;                           // wave's sample in pair
  const int bs = pair * 2 + sv;                     // global sample index
  const int obase = (wv & 1) * 64;                  // wave's O-half

  sacc[t] = 0.0f;

  // Per-lane global source = lane's A-frag: W[o=obase+m*16+lrow][lgrp*8..+8].
  // gll writes lane l at LDS base + l*16 -> image IS the frag layout.
  const unsigned short* wsrc =
      wt + (size_t)bs * 9 * CH * CH + (obase + lrow) * CH + lgrp * 8;

  // STAGE(S,P): stage S (tap=S>>2, ic=S&3): 64 O x 32 I = 4KB per wave,
  // 4 x 1KB gll chunks (m = O-subgroup of 16), wave-private buffer P.
#define STAGE(S, P) { \
    const unsigned short* g_ = wsrc + ((S) >> 2) * (CH * CH) + ((S) & 3) * 32; \
    unsigned short* l_ = wbuf + (wv * 2 + (P)) * 2048; \
    _Pragma("unroll") \
    for (int m_ = 0; m_ < 4; ++m_) \
      __builtin_amdgcn_global_load_lds( \
          (const __attribute__((address_space(1))) void*)(g_ + m_ * 16 * CH), \
          (__attribute__((address_space(3))) void*)(l_ + m_ * 512), 16, 0, 0); }

  // Issue stage 0 before patch staging; the barrier's vmcnt(0) drain
  // guarantees it resident after sync.
  STAGE(0, 0)

  // Patch staging: 2 samples x 100 rows x 2 halves of 64ch = 400 items.
  #pragma unroll
  for (int u = t; u < 400; u += 256) {
    const int samp = u / 200;
    const int v = u - samp * 200;
    const int row = v >> 1, half = v & 1;
    const int dh = row / 10, dw = row - dh * 10;
    const int h = h0 + dh - 1, w = w0 + dw - 1;
    const int bsl = pair * 2 + samp;
    unsigned short* ld = &patch[samp * 13600 + row * 136 + half * 64];
    if (h >= 0 && h < HH && w >= 0 && w < WW) {
      const unsigned short* src = in + ((size_t)((bsl * HH + h) * WW + w)) * CH + half * 64;
      if (FUSE) {
        #pragma unroll
        for (int j = 0; j < 8; ++j) {
          const bfv8 vv = *(const bfv8*)(src + j * 8);
          bfv8 o;
          #pragma unroll
          for (int k = 0; k < 8; ++k) {
            const int c = half * 64 + j * 8 + k;
            const float f = fmaxf(bf2f(vv[k]) * tab[c] + tab[CH + c], 0.0f);
            o[k] = f2bf(f);
          }
          *(bfv8*)(ld + j * 8) = o;
        }
      } else {
        #pragma unroll
        for (int j = 0; j < 8; ++j)
          *(bfv8*)(ld + j * 8) = *(const bfv8*)(src + j * 8);
      }
    } else {
      const bfv8 z = {0, 0, 0, 0, 0, 0, 0, 0};
      #pragma unroll
      for (int j = 0; j < 8; ++j) *(bfv8*)(ld + j * 8) = z;
    }
  }
  __syncthreads();

  f32x4 acc[4][4];
  #pragma unroll
  for (int m = 0; m < 4; ++m)
    #pragma unroll
    for (int n = 0; n < 4; ++n) acc[m][n] = (f32x4){0.f, 0.f, 0.f, 0.f};

  // COMPUTE(S,P): 4 A-frags lane-linear from wave-private buf P
  // (conflict-free), 4 B-frags from own sample's patch, 16 MFMA (K=32).
#define COMPUTE(S, P) { \
    const int tap_ = (S) >> 2, ic_ = (S) & 3; \
    const int pb_ = (pyl + tap_ / 3) * 10 + px + tap_ % 3; \
    const unsigned short* ab_ = wbuf + (wv * 2 + (P)) * 2048 + lane * 8; \
    const short8v a0_ = *(const short8v*)(ab_); \
    const short8v a1_ = *(const short8v*)(ab_ + 512); \
    const short8v a2_ = *(const short8v*)(ab_ + 1024); \
    const short8v a3_ = *(const short8v*)(ab_ + 1536); \
    _Pragma("unroll") \
    for (int nf = 0; nf < 4; ++nf) { \
      const short8v bfr = *(const short8v*)( \
          &patch[sv * 13600 + (pb_ + nf * 20) * 136 + ic_ * 32 + lgrp * 8]); \
      acc[0][nf] = __builtin_amdgcn_mfma_f32_16x16x32_bf16(a0_, bfr, acc[0][nf], 0, 0, 0); \
      acc[1][nf] = __builtin_amdgcn_mfma_f32_16x16x32_bf16(a1_, bfr, acc[1][nf], 0, 0, 0); \
      acc[2][nf] = __builtin_amdgcn_mfma_f32_16x16x32_bf16(a2_, bfr, acc[2][nf], 0, 0, 0); \
      acc[3][nf] = __builtin_amdgcn_mfma_f32_16x16x32_bf16(a3_, bfr, acc[3][nf], 0, 0, 0); \
    } }

  // RUN(S): [SB] issue S+1 -> wait vmcnt(4) (S resident, S+1 in flight)
  // [SB] compute S. 2-buffer rotation; WAR safe: COMPUTE(S)'s ds_reads are
  // lgkm-drained before its MFMAs issue, which precede STAGE(S+2) in
  // pinned program order.
#define RUN(S) \
    __builtin_amdgcn_sched_barrier(0); \
    STAGE((S) + 1, ((S) + 1) & 1) \
    asm volatile("s_waitcnt vmcnt(4)" ::: "memory"); \
    __builtin_amdgcn_sched_barrier(0); \
    COMPUTE(S, (S) & 1)

  RUN(0)  RUN(1)  RUN(2)  RUN(3)  RUN(4)  RUN(5)  RUN(6)  RUN(7)
  RUN(8)  RUN(9)  RUN(10) RUN(11) RUN(12) RUN(13) RUN(14) RUN(15)
  RUN(16) RUN(17) RUN(18) RUN(19) RUN(20) RUN(21) RUN(22) RUN(23)
  RUN(24) RUN(25) RUN(26) RUN(27) RUN(28) RUN(29) RUN(30) RUN(31)
  RUN(32) RUN(33) RUN(34)
  __builtin_amdgcn_sched_barrier(0);
  asm volatile("s_waitcnt vmcnt(0)" ::: "memory");
  __builtin_amdgcn_sched_barrier(0);
  COMPUTE(35, 1)
#undef RUN
#undef COMPUTE
#undef STAGE

  __syncthreads();   // patch reads done everywhere; reuse patch as output buffer

  // Stage D into LDS: obuf[sample][pixel p][ch] bf16, byte ^= ((p&3)<<5).
  char* obuf = (char*)patch;
  #pragma unroll
  for (int mf = 0; mf < 4; ++mf) {
    #pragma unroll
    for (int nf = 0; nf < 4; ++nf) {
      const f32x4 v = acc[mf][nf];
      bfv4 pk;
      #pragma unroll
      for (int r = 0; r < 4; ++r) pk[r] = f2bf(v[r]);
      const int p = (nf * 2 + pyl) * 8 + px;
      const int ch = obase + mf * 16 + lgrp * 4;
      int byte = sv * 16384 + p * 256 + ch * 2;
      byte ^= ((byte >> 8) & 3) << 5;
      *(bfv4*)(obuf + byte) = pk;
    }
  }

  // Fused BN stat partials: shuffle-reduce over the 16 pixel lanes,
  // LDS-accumulate (both samples' waves sum into the same channel -- BN sums
  // over the batch dim), then one non-atomic 256-float row per block.
  #pragma unroll
  for (int mf = 0; mf < 4; ++mf) {
    f32x4 sv4 = {0.f, 0.f, 0.f, 0.f}, qv4 = {0.f, 0.f, 0.f, 0.f};
    #pragma unroll
    for (int nf = 0; nf < 4; ++nf) {
      const f32x4 v = acc[mf][nf];
      sv4 += v;
      qv4 += v * v;
    }
    #pragma unroll
    for (int r = 0; r < 4; ++r) {
      float sv_ = sv4[r], qv_ = qv4[r];
      sv_ += __shfl_xor(sv_, 1, 64);  qv_ += __shfl_xor(qv_, 1, 64);
      sv_ += __shfl_xor(sv_, 2, 64);  qv_ += __shfl_xor(qv_, 2, 64);
      sv_ += __shfl_xor(sv_, 4, 64);  qv_ += __shfl_xor(qv_, 4, 64);
      sv_ += __shfl_xor(sv_, 8, 64);  qv_ += __shfl_xor(qv_, 8, 64);
      if (lrow == 0) {
        const int ch = obase + mf * 16 + lgrp * 4 + r;
        atomicAdd(&sacc[ch], sv_);
        atomicAdd(&sacc[CH + ch], qv_);
      }
    }
  }

  __syncthreads();

  partials[(size_t)blockIdx.x * 256 + t] = sacc[t];

  // Copy out: 8 passes x 256 threads x 16B (2 samples x 64 px x 128 ch).
  #pragma unroll
  for (int j = 0; j < 8; ++j) {
    const int u = j * 256 + t;           // 16B unit index, 0..2047
    int byte = u * 16;
    byte ^= ((byte >> 8) & 3) << 5;
    const bfv8 v = *(const bfv8*)(obuf + byte);
    const int samp = u >> 10, pix = (u >> 4) & 63;
    const int py = pix >> 3, pxx = pix & 7;
    const int bsl = pair * 2 + samp;
    *(bfv8*)(outp + ((size_t)((bsl * HH + h0 + py) * WW + (w0 + pxx))) * CH +
             (u & 15) * 8) = v;
  }
}

// ---------------------------------------------------------------------------
// K-red: reduce partials[1568][256] -> st[256]. 32 blocks x 256 thr.
__global__ __launch_bounds__(256)
void stat_reduce(const float* __restrict__ partials, float* __restrict__ st) {
  const int t = threadIdx.x;
  float s = 0.0f;
  const int i0 = blockIdx.x * (NCONVBLK / 32);
  for (int i = 0; i < NCONVBLK / 32; ++i)
    s += partials[(size_t)(i0 + i) * 256 + t];
  atomicAdd(&st[t], s);
}

// ---------------------------------------------------------------------------
// K4/K6: per-channel BN stats -> scale/shift tables.
__global__ __launch_bounds__(128)
void bn_stats(const float* __restrict__ st, const float* __restrict__ gamma,
              const float* __restrict__ beta, float* __restrict__ tab) {
  const int c = threadIdx.x;
  const float inv = 1.0f / NPIXF;
  const float mean = st[c] * inv;
  const float var = st[CH + c] * inv - mean * mean;
  const float s = gamma[c] / sqrtf(var + 1e-5f);
  tab[c] = s;
  tab[CH + c] = beta[c] - mean * s;
}

// ---------------------------------------------------------------------------
// K7: out = relu(scale2*y2 + shift2 + residual), NHWC bf16 -> NCHW fp32.
// BF16RES: residual from xT (bf16 NHWC, 51MB) instead of x (fp32 NCHW, 205MB).
template<bool BF16RES>
__global__ __launch_bounds__(256)
void final_kernel(const unsigned short* __restrict__ y2,
                  const unsigned short* __restrict__ xbf,
                  const float* __restrict__ x,
                  const float* __restrict__ tab, float* __restrict__ out) {
  const int bid = blockIdx.x;
  const int b = bid / 14, hq = bid % 14;
  const int h = hq * 4 + (threadIdx.x >> 6);
  const int w = threadIdx.x & 63;
  if (w >= WW) return;
  const unsigned short* ys = y2 + ((size_t)(b * HH + h) * WW + w) * CH;
  const unsigned short* rs = xbf + ((size_t)(b * HH + h) * WW + w) * CH;
  const float* xs = x + (size_t)b * CH * HWPIX + h * WW + w;
  float* os = out + (size_t)b * CH * HWPIX + h * WW + w;
  #pragma unroll 4
  for (int c = 0; c < CH; ++c) {
    const float v = bf2f(ys[c]);
    const float res = BF16RES ? bf2f(rs[c]) : xs[(size_t)c * HWPIX];
    const float r = v * tab[c] + tab[CH + c] + res;
    os[(size_t)c * HWPIX] = fmaxf(r, 0.0f);
  }
}

// ---------------------------------------------------------------------------
extern "C" void kernel_launch(void* const* d_in, const int* in_sizes, int n_in,
                              void* d_out, int out_size, void* d_ws, size_t ws_size,
                              hipStream_t stream) {
  const float* x  = (const float*)d_in[0];
  const float* w1 = (const float*)d_in[1];
  const float* w2 = (const float*)d_in[2];
  const float* g1 = (const float*)d_in[3];
  const float* b1 = (const float*)d_in[4];
  const float* g2 = (const float*)d_in[5];
  const float* b2 = (const float*)d_in[6];
  float* out = (float*)d_out;

  // Workspace layout (bytes):
  //   xT   0            51,380,224
  //   y1   51,380,224   51,380,224
  //   w1b  102,760,448  18,874,368
  //   w2b  121,634,816  18,874,368
  //   p1   140,509,184  3,211,264   (1568 x 256 floats used)
  //   p2   143,720,448  3,211,264
  //   st   146,931,712  4,096   (st1|st2|tab1|tab2, 256 floats each)
  //   y2   146,935,808  51,380,224  (optional, if ws_size allows)
  char* ws = (char*)d_ws;
  unsigned short* xT  = (unsigned short*)(ws);
  unsigned short* y1  = (unsigned short*)(ws + 51380224);
  unsigned short* w1b = (unsigned short*)(ws + 102760448);
  unsigned short* w2b = (unsigned short*)(ws + 121634816);
  float*          p1  = (float*)(ws + 140509184);
  float*          p2  = (float*)(ws + 143720448);
  float*          st  = (float*)(ws + 146931712);
  const bool sepY2 = ws_size >= (size_t)146935808 + 51380224;
  unsigned short* y2  = sepY2 ? (unsigned short*)(ws + 146935808) : xT;

  (void)hipMemsetAsync(st, 0, 2048, stream);  // zero st1+st2

  hipLaunchKernelGGL(prep_x, dim3(NB * 14), dim3(256), 0, stream, x, xT);
  hipLaunchKernelGGL(prep_w, dim3(1024), dim3(256), 0, stream, w1, w2, w1b, w2b);
  hipLaunchKernelGGL((conv_kernel<false>), dim3(NCONVBLK), dim3(256), 0, stream,
                     xT, w1b, y1, p1, (const float*)nullptr);
  hipLaunchKernelGGL(stat_reduce, dim3(32), dim3(256), 0, stream, p1, st);
  hipLaunchKernelGGL(bn_stats, dim3(1), dim3(128), 0, stream, st, g1, b1, st + 512);
  hipLaunchKernelGGL((conv_kernel<true>), dim3(NCONVBLK), dim3(256), 0, stream,
                     y1, w2b, y2, p2, st + 512);
  hipLaunchKernelGGL(stat_reduce, dim3(32), dim3(256), 0, stream, p2, st + 256);
  hipLaunchKernelGGL(bn_stats, dim3(1), dim3(128), 0, stream, st + 256, g2, b2, st + 768);
  if (sepY2) {
    hipLaunchKernelGGL((final_kernel<true>), dim3(NB * 14), dim3(256), 0, stream,
                       y2, xT, x, st + 768, out);
  } else {
    hipLaunchKernelGGL((final_kernel<false>), dim3(NB * 14), dim3(256), 0, stream,
                       y2, xT, x, st + 768, out);
  }
}

// Round 12
// 366.629 us; speedup vs baseline: 1.3766x; 1.3766x over previous
//
#include <hip/hip_runtime.h>
#include <hip/hip_bf16.h>
#include <stdint.h>
#include <stddef.h>

// Problem dims (fixed): B=64, C=128, H=W=56, 3x3 conv pad=1 stride=1.
#define CH 128
#define HH 56
#define WW 56
#define HWPIX (HH*WW)        // 3136
#define NB 64
#define NPIXF 200704.0f      // B*H*W
#define NCONVBLK 1792        // 64 samples x 28 tiles (14x8 px)

typedef __attribute__((ext_vector_type(8))) short short8v;    // 8 bf16 -> MFMA A/B frag
typedef __attribute__((ext_vector_type(8))) unsigned short bfv8;
typedef __attribute__((ext_vector_type(4))) unsigned short bfv4;
typedef __attribute__((ext_vector_type(4))) float f32x4;

__device__ __forceinline__ unsigned short f2bf(float f) {
  unsigned int u = __float_as_uint(f);
  u += 0x7fffu + ((u >> 16) & 1u);            // RNE
  return (unsigned short)(u >> 16);
}
__device__ __forceinline__ float bf2f(unsigned short s) {
  return __uint_as_float(((unsigned int)s) << 16);
}

// ---------------------------------------------------------------------------
// K1: x NCHW fp32 -> NHWC bf16 (LDS transpose, coalesced 16B/lane writes).
__global__ __launch_bounds__(256)
void prep_x(const float* __restrict__ x, unsigned short* __restrict__ xT) {
  __shared__ unsigned short tile[4 * 56 * 128];
  const int bid = blockIdx.x;
  const int b = bid / 14, hq = bid % 14;
  const int hl = threadIdx.x >> 6;
  const int h = hq * 4 + hl;
  const int w = threadIdx.x & 63;
  if (w < WW) {
    const float* src = x + (size_t)b * CH * HWPIX + h * WW + w;
    const int pos = hl * WW + w;
    #pragma unroll 4
    for (int c0 = 0; c0 < CH; c0 += 8) {
      bfv8 v;
      #pragma unroll
      for (int k = 0; k < 8; ++k) v[k] = f2bf(src[(size_t)(c0 + k) * HWPIX]);
      const int idx = (pos * CH + c0) ^ ((pos & 7) << 3);
      *(bfv8*)(tile + idx) = v;
    }
  }
  __syncthreads();
  unsigned short* out = xT + (size_t)(b * HH + hq * 4) * WW * CH;
  #pragma unroll
  for (int j = 0; j < 14; ++j) {
    const int u = j * 256 + threadIdx.x;
    const int idx = (u * 8) ^ (((u >> 4) & 7) << 3);
    *(bfv8*)(out + u * 8) = *(const bfv8*)(tile + idx);
  }
}

// ---------------------------------------------------------------------------
// K2: weights [B,O,I,3,3] fp32 -> [B,tap,O,I] bf16 (dense reads, 16B writes).
__global__ __launch_bounds__(256)
void prep_w(const float* __restrict__ w1, const float* __restrict__ w2,
            unsigned short* __restrict__ o1, unsigned short* __restrict__ o2) {
  __shared__ unsigned short lw[18432];
  const int id = blockIdx.x;
  const int which = id >> 9;
  const int b = (id >> 3) & 63, ck = id & 7;
  const float* src = (which ? w2 : w1) + ((size_t)b * 16384 + ck * 2048) * 9;
  unsigned short* dst = (which ? o2 : o1);
  const int t = threadIdx.x;
  #pragma unroll
  for (int j = 0; j < 72; ++j)
    lw[j * 256 + t] = f2bf(src[j * 256 + t]);
  __syncthreads();
  const int ol = t >> 4, oct = t & 15;
  #pragma unroll
  for (int tap = 0; tap < 9; ++tap) {
    bfv8 v;
    #pragma unroll
    for (int k = 0; k < 8; ++k) v[k] = lw[(ol * 128 + oct * 8 + k) * 9 + tap];
    *(bfv8*)(dst + ((size_t)(b * 9 + tap) * CH + ck * 16 + ol) * CH + oct * 8) = v;
  }
}

// ---------------------------------------------------------------------------
// K3/K5: per-sample conv, implicit GEMM.
// R20: R17 PIPELINE + 14x8 TILE. Signal across R8..R19: time is invariant
// (~153us) across occupancy (R16), depth (R17), DS volume (R19 confounded),
// reg-vs-LDS weights (R8 vs R16) -- but the per-CU VMEM weight-load count
// (~3.5k/CU, ~100cyc each) never varied: every 64px block refetches its
// sample's full 294KB weights (49 blocks/sample = 14.4MB/sample via VMEM).
// Fix: 14x8 tile (112px) -> blocks 3136->1792, weight gll count -43%,
// prologue/epilogue amortized 1.75x. R14 tried this and SPILLED because
// weights were VGPR-resident; now they're LDS-resident (R17: VGPR 68), so
// acc[2][7]=56 AGPR + ~130 arch ~= 186 < 256 combined budget at (256,2).
// LDS: patch 160x136 (43,520) + wbuf 4wv x 3buf x 2KB (24,576) + sacc 1,024
// = 69,120 -> 2 blocks/CU (R8's proven-sufficient 2 waves/SIMD). Pipeline
// discipline byte-identical to proven-correct R17 (3-buf, depth-2, SBs).
// Predict: conv 153->105-125, MfmaUtil 20-26, VGPR 120-140, FETCH ~34MB
// (>60MB = spill = abort). Pre-committed null: conv >=145 clean -> VMEM-count
// model dead, conv converged, pivot to aux kernels.
template<bool FUSE>
__global__ __launch_bounds__(256, 2)
void conv_kernel(const unsigned short* __restrict__ in,
                 const unsigned short* __restrict__ wt,
                 unsigned short* __restrict__ outp,
                 float* __restrict__ partials,
                 const float* __restrict__ tab) {   // [256]: scale | shift (FUSE)
  __shared__ __align__(16) unsigned short patch[21760];  // 160 rows x 136
  __shared__ __align__(16) unsigned short wbuf[12288];   // 4 wv x 3 buf x 1024
  __shared__ float sacc[256];                            // sum[128] | sumsq[128]
  const int xcd = blockIdx.x & 7;
  const int q = blockIdx.x >> 3;                    // 0..223
  const int s = q / 28;
  const int tile = q - s * 28;                      // 0..27
  const int b = s * 8 + xcd;
  const int ty = tile / 7, tx = tile % 7;
  const int h0 = ty * 14, w0 = tx * 8;
  const int t = threadIdx.x;

  const int lane = t & 63, wv = t >> 6;
  const int lrow = lane & 15, lgrp = lane >> 4;
  const int px = lrow & 7, pyl = lrow >> 3;

  sacc[t] = 0.0f;

  // Per-lane global source = lane's A-frag: W[o=wv*32+lrow][lgrp*8..+8].
  // gll writes lane l at LDS base + l*16 -> image IS the frag layout.
  const unsigned short* wsrc =
      wt + (size_t)b * 9 * CH * CH + (wv * 32 + lrow) * CH + lgrp * 8;

  // STAGE(S,P): stage S (tap=S>>2, ic=S&3; 32 O x 32 I = 2KB/wave) into
  // wave-private buffer P. instr0: O rows +0..15; instr1: +16..31.
#define STAGE(S, P) { \
    const unsigned short* g_ = wsrc + ((S) >> 2) * (CH * CH) + ((S) & 3) * 32; \
    unsigned short* l_ = wbuf + (wv * 3 + (P)) * 1024; \
    __builtin_amdgcn_global_load_lds( \
        (const __attribute__((address_space(1))) void*)g_, \
        (__attribute__((address_space(3))) void*)l_, 16, 0, 0); \
    __builtin_amdgcn_global_load_lds( \
        (const __attribute__((address_space(1))) void*)(g_ + 16 * CH), \
        (__attribute__((address_space(3))) void*)(l_ + 512), 16, 0, 0); \
  }

  // Issue stage 0 before patch staging; the barrier's vmcnt(0) drain
  // guarantees it resident after sync.
  STAGE(0, 0)

  // Patch staging: 160 rows x 2 halves of 64ch = 320 items.
  #pragma unroll
  for (int u = t; u < 320; u += 256) {
    const int row = u >> 1, half = u & 1;
    const int dh = row / 10, dw = row - dh * 10;
    const int h = h0 + dh - 1, w = w0 + dw - 1;
    unsigned short* ld = &patch[row * 136 + half * 64];
    if (h >= 0 && h < HH && w >= 0 && w < WW) {
      const unsigned short* src = in + ((size_t)((b * HH + h) * WW + w)) * CH + half * 64;
      if (FUSE) {
        #pragma unroll
        for (int j = 0; j < 8; ++j) {
          const bfv8 v = *(const bfv8*)(src + j * 8);
          bfv8 o;
          #pragma unroll
          for (int k = 0; k < 8; ++k) {
            const int c = half * 64 + j * 8 + k;
            const float f = fmaxf(bf2f(v[k]) * tab[c] + tab[CH + c], 0.0f);
            o[k] = f2bf(f);
          }
          *(bfv8*)(ld + j * 8) = o;
        }
      } else {
        #pragma unroll
        for (int j = 0; j < 8; ++j)
          *(bfv8*)(ld + j * 8) = *(const bfv8*)(src + j * 8);
      }
    } else {
      const bfv8 z = {0, 0, 0, 0, 0, 0, 0, 0};
      #pragma unroll
      for (int j = 0; j < 8; ++j) *(bfv8*)(ld + j * 8) = z;
    }
  }
  __syncthreads();

  f32x4 acc[2][7];
  #pragma unroll
  for (int m = 0; m < 2; ++m)
    #pragma unroll
    for (int n = 0; n < 7; ++n) acc[m][n] = (f32x4){0.f, 0.f, 0.f, 0.f};

  // Refill the pipeline after the barrier drain: stage 1 in flight now.
  STAGE(1, 1)

  // COMPUTE(S,P): 2 A-frags lane-linear from wave-private buf P
  // (conflict-free), 7 B-frags from patch, 14 MFMA (K=32 chunk ic).
#define COMPUTE(S, P) { \
    const int tap_ = (S) >> 2, ic_ = (S) & 3; \
    const int pb_ = (pyl + tap_ / 3) * 10 + px + tap_ % 3; \
    const unsigned short* ab_ = wbuf + (wv * 3 + (P)) * 1024 + lane * 8; \
    const short8v a0_ = *(const short8v*)(ab_); \
    const short8v a1_ = *(const short8v*)(ab_ + 512); \
    _Pragma("unroll") \
    for (int nf = 0; nf < 7; ++nf) { \
      const short8v bfr = *(const short8v*)( \
          &patch[(pb_ + nf * 20) * 136 + ic_ * 32 + lgrp * 8]); \
      acc[0][nf] = __builtin_amdgcn_mfma_f32_16x16x32_bf16(a0_, bfr, acc[0][nf], 0, 0, 0); \
      acc[1][nf] = __builtin_amdgcn_mfma_f32_16x16x32_bf16(a1_, bfr, acc[1][nf], 0, 0, 0); \
    } }

  // RUN(S): [SB] issue S+2 -> wait vmcnt(4) (S resident; S+1,S+2 in flight)
  // [SB] compute S. Depth-2, 3-buffer rotation (proven correct in R17).
#define RUN(S) \
    __builtin_amdgcn_sched_barrier(0); \
    STAGE((S) + 2, ((S) + 2) % 3) \
    asm volatile("s_waitcnt vmcnt(4)" ::: "memory"); \
    __builtin_amdgcn_sched_barrier(0); \
    COMPUTE(S, (S) % 3)

  RUN(0)  RUN(1)  RUN(2)  RUN(3)  RUN(4)  RUN(5)  RUN(6)  RUN(7)
  RUN(8)  RUN(9)  RUN(10) RUN(11) RUN(12) RUN(13) RUN(14) RUN(15)
  RUN(16) RUN(17) RUN(18) RUN(19) RUN(20) RUN(21) RUN(22) RUN(23)
  RUN(24) RUN(25) RUN(26) RUN(27) RUN(28) RUN(29) RUN(30) RUN(31)
  RUN(32) RUN(33)
  // Tail: stages 34,35 already in flight.
  __builtin_amdgcn_sched_barrier(0);
  asm volatile("s_waitcnt vmcnt(2)" ::: "memory");
  __builtin_amdgcn_sched_barrier(0);
  COMPUTE(34, 1)
  __builtin_amdgcn_sched_barrier(0);
  asm volatile("s_waitcnt vmcnt(0)" ::: "memory");
  __builtin_amdgcn_sched_barrier(0);
  COMPUTE(35, 2)
#undef RUN
#undef COMPUTE
#undef STAGE

  __syncthreads();   // patch reads done everywhere; reuse patch as output buffer

  // Stage D into LDS: obuf[pixel p 0..111][ch 0..127] bf16, byte ^= swizzle.
  char* obuf = (char*)patch;
  #pragma unroll
  for (int mf = 0; mf < 2; ++mf) {
    #pragma unroll
    for (int nf = 0; nf < 7; ++nf) {
      const f32x4 v = acc[mf][nf];
      bfv4 pk;
      #pragma unroll
      for (int r = 0; r < 4; ++r) pk[r] = f2bf(v[r]);
      const int p = (nf * 2 + pyl) * 8 + px;
      const int ch = wv * 32 + mf * 16 + lgrp * 4;
      int byte = p * 256 + ch * 2;
      byte ^= ((byte >> 8) & 3) << 5;
      *(bfv4*)(obuf + byte) = pk;
    }
  }

  // Fused BN stat partials: shuffle-reduce over the 16 pixel lanes,
  // LDS-accumulate, then ONE non-atomic 256-float row per block.
  #pragma unroll
  for (int mf = 0; mf < 2; ++mf) {
    f32x4 sv4 = {0.f, 0.f, 0.f, 0.f}, qv4 = {0.f, 0.f, 0.f, 0.f};
    #pragma unroll
    for (int nf = 0; nf < 7; ++nf) {
      const f32x4 v = acc[mf][nf];
      sv4 += v;
      qv4 += v * v;
    }
    #pragma unroll
    for (int r = 0; r < 4; ++r) {
      float sv = sv4[r], qv = qv4[r];
      sv += __shfl_xor(sv, 1, 64);  qv += __shfl_xor(qv, 1, 64);
      sv += __shfl_xor(sv, 2, 64);  qv += __shfl_xor(qv, 2, 64);
      sv += __shfl_xor(sv, 4, 64);  qv += __shfl_xor(qv, 4, 64);
      sv += __shfl_xor(sv, 8, 64);  qv += __shfl_xor(qv, 8, 64);
      if (lrow == 0) {
        const int ch = wv * 32 + mf * 16 + lgrp * 4 + r;
        atomicAdd(&sacc[ch], sv);        // LDS atomic, 8 per thread-group
        atomicAdd(&sacc[CH + ch], qv);
      }
    }
  }

  __syncthreads();

  partials[(size_t)blockIdx.x * 256 + t] = sacc[t];

  // Copy out: 7 passes x 256 threads x 16B (112 px x 128 ch).
  #pragma unroll
  for (int j = 0; j < 7; ++j) {
    const int u = j * 256 + t;           // 16B unit index, 0..1791
    int byte = u * 16;
    byte ^= ((byte >> 8) & 3) << 5;
    const bfv8 v = *(const bfv8*)(obuf + byte);
    const int pix = u >> 4, py = pix >> 3, pxx = pix & 7;
    *(bfv8*)(outp + ((size_t)((b * HH + h0 + py) * WW + (w0 + pxx))) * CH +
             (u & 15) * 8) = v;
  }
}

// ---------------------------------------------------------------------------
// K-red: reduce partials[1792][256] -> st[256]. 32 blocks x 256 thr.
__global__ __launch_bounds__(256)
void stat_reduce(const float* __restrict__ partials, float* __restrict__ st) {
  const int t = threadIdx.x;
  float s = 0.0f;
  const int i0 = blockIdx.x * (NCONVBLK / 32);
  for (int i = 0; i < NCONVBLK / 32; ++i)
    s += partials[(size_t)(i0 + i) * 256 + t];
  atomicAdd(&st[t], s);
}

// ---------------------------------------------------------------------------
// K4/K6: per-channel BN stats -> scale/shift tables.
__global__ __launch_bounds__(128)
void bn_stats(const float* __restrict__ st, const float* __restrict__ gamma,
              const float* __restrict__ beta, float* __restrict__ tab) {
  const int c = threadIdx.x;
  const float inv = 1.0f / NPIXF;
  const float mean = st[c] * inv;
  const float var = st[CH + c] * inv - mean * mean;
  const float s = gamma[c] / sqrtf(var + 1e-5f);
  tab[c] = s;
  tab[CH + c] = beta[c] - mean * s;
}

// ---------------------------------------------------------------------------
// K7: out = relu(scale2*y2 + shift2 + residual), NHWC bf16 -> NCHW fp32.
// BF16RES: residual from xT (bf16 NHWC, 51MB) instead of x (fp32 NCHW, 205MB).
template<bool BF16RES>
__global__ __launch_bounds__(256)
void final_kernel(const unsigned short* __restrict__ y2,
                  const unsigned short* __restrict__ xbf,
                  const float* __restrict__ x,
                  const float* __restrict__ tab, float* __restrict__ out) {
  const int bid = blockIdx.x;
  const int b = bid / 14, hq = bid % 14;
  const int h = hq * 4 + (threadIdx.x >> 6);
  const int w = threadIdx.x & 63;
  if (w >= WW) return;
  const unsigned short* ys = y2 + ((size_t)(b * HH + h) * WW + w) * CH;
  const unsigned short* rs = xbf + ((size_t)(b * HH + h) * WW + w) * CH;
  const float* xs = x + (size_t)b * CH * HWPIX + h * WW + w;
  float* os = out + (size_t)b * CH * HWPIX + h * WW + w;
  #pragma unroll 4
  for (int c = 0; c < CH; ++c) {
    const float v = bf2f(ys[c]);
    const float res = BF16RES ? bf2f(rs[c]) : xs[(size_t)c * HWPIX];
    const float r = v * tab[c] + tab[CH + c] + res;
    os[(size_t)c * HWPIX] = fmaxf(r, 0.0f);
  }
}

// ---------------------------------------------------------------------------
extern "C" void kernel_launch(void* const* d_in, const int* in_sizes, int n_in,
                              void* d_out, int out_size, void* d_ws, size_t ws_size,
                              hipStream_t stream) {
  const float* x  = (const float*)d_in[0];
  const float* w1 = (const float*)d_in[1];
  const float* w2 = (const float*)d_in[2];
  const float* g1 = (const float*)d_in[3];
  const float* b1 = (const float*)d_in[4];
  const float* g2 = (const float*)d_in[5];
  const float* b2 = (const float*)d_in[6];
  float* out = (float*)d_out;

  // Workspace layout (bytes):
  //   xT   0            51,380,224
  //   y1   51,380,224   51,380,224
  //   w1b  102,760,448  18,874,368
  //   w2b  121,634,816  18,874,368
  //   p1   140,509,184  3,211,264   (1792 x 256 floats used)
  //   p2   143,720,448  3,211,264
  //   st   146,931,712  4,096   (st1|st2|tab1|tab2, 256 floats each)
  //   y2   146,935,808  51,380,224  (optional, if ws_size allows)
  char* ws = (char*)d_ws;
  unsigned short* xT  = (unsigned short*)(ws);
  unsigned short* y1  = (unsigned short*)(ws + 51380224);
  unsigned short* w1b = (unsigned short*)(ws + 102760448);
  unsigned short* w2b = (unsigned short*)(ws + 121634816);
  float*          p1  = (float*)(ws + 140509184);
  float*          p2  = (float*)(ws + 143720448);
  float*          st  = (float*)(ws + 146931712);
  const bool sepY2 = ws_size >= (size_t)146935808 + 51380224;
  unsigned short* y2  = sepY2 ? (unsigned short*)(ws + 146935808) : xT;

  (void)hipMemsetAsync(st, 0, 2048, stream);  // zero st1+st2

  hipLaunchKernelGGL(prep_x, dim3(NB * 14), dim3(256), 0, stream, x, xT);
  hipLaunchKernelGGL(prep_w, dim3(1024), dim3(256), 0, stream, w1, w2, w1b, w2b);
  hipLaunchKernelGGL((conv_kernel<false>), dim3(NCONVBLK), dim3(256), 0, stream,
                     xT, w1b, y1, p1, (const float*)nullptr);
  hipLaunchKernelGGL(stat_reduce, dim3(32), dim3(256), 0, stream, p1, st);
  hipLaunchKernelGGL(bn_stats, dim3(1), dim3(128), 0, stream, st, g1, b1, st + 512);
  hipLaunchKernelGGL((conv_kernel<true>), dim3(NCONVBLK), dim3(256), 0, stream,
                     y1, w2b, y2, p2, st + 512);
  hipLaunchKernelGGL(stat_reduce, dim3(32), dim3(256), 0, stream, p2, st + 256);
  hipLaunchKernelGGL(bn_stats, dim3(1), dim3(128), 0, stream, st + 256, g2, b2, st + 768);
  if (sepY2) {
    hipLaunchKernelGGL((final_kernel<true>), dim3(NB * 14), dim3(256), 0, stream,
                       y2, xT, x, st + 768, out);
  } else {
    hipLaunchKernelGGL((final_kernel<false>), dim3(NB * 14), dim3(256), 0, stream,
                       y2, xT, x, st + 768, out);
  }
}